// Round 14
// baseline (92.624 us; speedup 1.0000x reference)
//
#include <hip/hip_runtime.h>

// E-MHSA (PVT-style spatial-reduction attention), MI355X/gfx950.
// B=4, N=3136, C=384, H=12, d=32, SR=2 -> Nk=784.
// R14 = R10 (last passing, 79.2us) + bijective XCD swizzle (1200=8x150) +
// exp2f (compiler-managed TRANS hazards, replaces raw v_exp asm) + s_setprio
// around PV cluster. 512-thread branch (R11-R13) abandoned: unlocalizable
// schedule-dependent NaN. Structure: attn QBLK=128 / 4 waves / KVBLK=64 /
// 3-buffer depth-2 counted-vmcnt / register-resident P / κ'-permuted V;
// GEMMs 128x128 (q/out) + 64x128 (k/v) tiles.

typedef __bf16 bf16x8 __attribute__((ext_vector_type(8)));
typedef unsigned short u16x8 __attribute__((ext_vector_type(8)));
typedef float f32x4 __attribute__((ext_vector_type(4)));

#define NTOK 3136
#define NKV 784
#define CCH 384
#define KPAD 832                   // 13 * 64, κ'-row stride for vt
#define SC2 0.25503472078024693f   // 32^-0.5 * log2(e), folded into Q

// fence-carrying wait+barrier (N = vmcnt to leave outstanding)
#define WAIT_BAR(N) asm volatile("s_waitcnt vmcnt(" #N ")\n\ts_barrier" ::: "memory")

__device__ __forceinline__ unsigned short f2b(float f) {
  union { float f; unsigned u; } v; v.f = f;
  unsigned r = v.u + 0x7fffu + ((v.u >> 16) & 1u);   // RNE
  return (unsigned short)(r >> 16);
}

__device__ __forceinline__ bf16x8 ldsb8(const unsigned short* p) {
  u16x8 v = *(const u16x8*)p;
  return __builtin_bit_cast(bf16x8, v);
}

// async global->LDS, 16B/lane; LDS dest = wave-uniform base + lane*16
__device__ __forceinline__ void gload16(const void* g, void* lds) {
  auto* g1 = reinterpret_cast<const __attribute__((address_space(1))) unsigned int*>(
      reinterpret_cast<uintptr_t>(g));
  auto* l3 = reinterpret_cast<__attribute__((address_space(3))) unsigned int*>(
      reinterpret_cast<uintptr_t>(lds));
  __builtin_amdgcn_global_load_lds(g1, l3, 16, 0, 0);
}

// ---------------- fused prep ----------------
// [0,1176): pool+bn + cast-x ; [1176,1320): cast weights ; [1320,1416): zero vt pad
__global__ __launch_bounds__(256) void prep_kernel(
    const float* __restrict__ x, const float* __restrict__ gam,
    const float* __restrict__ bet, const float* __restrict__ mea,
    const float* __restrict__ var,
    const float* __restrict__ Wq, const float* __restrict__ Wk,
    const float* __restrict__ Wv, const float* __restrict__ Wp,
    unsigned short* __restrict__ xb, unsigned short* __restrict__ xpb,
    unsigned short* __restrict__ wq, unsigned short* __restrict__ wk,
    unsigned short* __restrict__ wv, unsigned short* __restrict__ wp,
    unsigned short* __restrict__ vt) {
  int bid = blockIdx.x;
  if (bid < 1176) {
    int i = bid * 256 + threadIdx.x;       // < 301056 = 4*784*96
    int c4 = i % 96;
    int row = i / 96;                      // b*784 + nk
    int b = row / NKV, nk = row - b * NKV;
    const float4* x4 = (const float4*)x;
    size_t base = ((size_t)(b * NTOK + nk * 4)) * 96 + c4;
    float sx = 0.f, sy = 0.f, sz = 0.f, sw = 0.f;
#pragma unroll
    for (int r = 0; r < 4; ++r) {
      float4 v = x4[base + (size_t)r * 96];
      ushort4 cv; cv.x = f2b(v.x); cv.y = f2b(v.y); cv.z = f2b(v.z); cv.w = f2b(v.w);
      ((ushort4*)xb)[base + (size_t)r * 96] = cv;
      sx += v.x; sy += v.y; sz += v.z; sw += v.w;
    }
    float4 g4 = ((const float4*)gam)[c4];
    float4 b4 = ((const float4*)bet)[c4];
    float4 m4 = ((const float4*)mea)[c4];
    float4 v4 = ((const float4*)var)[c4];
    ushort4 r4;
    r4.x = f2b((sx * 0.25f - m4.x) * rsqrtf(v4.x + 1e-5f) * g4.x + b4.x);
    r4.y = f2b((sy * 0.25f - m4.y) * rsqrtf(v4.y + 1e-5f) * g4.y + b4.y);
    r4.z = f2b((sz * 0.25f - m4.z) * rsqrtf(v4.z + 1e-5f) * g4.z + b4.z);
    r4.w = f2b((sw * 0.25f - m4.w) * rsqrtf(v4.w + 1e-5f) * g4.w + b4.w);
    ((ushort4*)xpb)[i] = r4;
  } else if (bid < 1320) {
    int i = (bid - 1176) * 256 + threadIdx.x;   // < 36864 = 147456/4
    float4 va = ((const float4*)Wq)[i];
    float4 vb = ((const float4*)Wk)[i];
    float4 vc = ((const float4*)Wv)[i];
    float4 vd = ((const float4*)Wp)[i];
    ushort4 ra; ra.x = f2b(va.x); ra.y = f2b(va.y); ra.z = f2b(va.z); ra.w = f2b(va.w);
    ushort4 rb; rb.x = f2b(vb.x); rb.y = f2b(vb.y); rb.z = f2b(vb.z); rb.w = f2b(vb.w);
    ushort4 rc; rc.x = f2b(vc.x); rc.y = f2b(vc.y); rc.z = f2b(vc.z); rc.w = f2b(vc.w);
    ushort4 rd; rd.x = f2b(vd.x); rd.y = f2b(vd.y); rd.z = f2b(vd.z); rd.w = f2b(vd.w);
    ((ushort4*)wq)[i] = ra; ((ushort4*)wk)[i] = rb;
    ((ushort4*)wv)[i] = rc; ((ushort4*)wp)[i] = rd;
  } else {
    // zero vt κ'-pad [768,832) for all 1536 (b,h,d) rows
    int i = (bid - 1320) * 256 + threadIdx.x;   // < 24576
    int row = i >> 4, quad = i & 15;
    ushort4 z; z.x = 0; z.y = 0; z.z = 0; z.w = 0;
    *(ushort4*)&vt[(size_t)row * KPAD + 768 + quad * 4] = z;
  }
}

// ---------------- GEMM body: C[MR x 128] = A[MRxK] * W[128 cols][K]^T + bias --
// MR = 64 or 128. LDS [kchunk][row] 16B units, conflict-free b128 reads.
// 3-buffer pipeline, depth-2 prefetch, counted vmcnt mid-loop, fully
// unrolled, fenced barriers.
// epi: 0 bf16 row-major (scaled by oscale), 1 bf16 κ'-scatter vt, 2 fp32.
template <int MR>
__device__ __forceinline__ void gemm_body(
    const unsigned short* __restrict__ A, const unsigned short* __restrict__ Bt,
    const float* __restrict__ bias, void* __restrict__ out,
    int row0, int col0, int epi, float oscale,
    unsigned short* sA, unsigned short* sB) {
  constexpr int ABUF = MR * 32;          // ushorts per A buffer
  constexpr int MH = MR / 2;             // rows per wave
  constexpr int NM = MR / 32;            // A fragments per wave
  const int t = threadIdx.x, w = t >> 6, l = t & 63;
  const int wr = w >> 1, wc = w & 1;
  const int hi = l >> 4, c = l & 15;

  f32x4 acc[NM][4];
#pragma unroll
  for (int m = 0; m < NM; ++m)
#pragma unroll
    for (int n = 0; n < 4; ++n) acc[m][n] = (f32x4){0.f, 0.f, 0.f, 0.f};

  const unsigned short* Abase = A + (size_t)(row0 + l) * CCH + w * 8;
  const unsigned short* Abase2 = A + (size_t)(row0 + (MR == 128 ? 64 : 0) + l) * CCH + w * 8;
  const unsigned short* B0base = Bt + (size_t)(col0 + l) * CCH + w * 8;
  const unsigned short* B1base = Bt + (size_t)(col0 + 64 + l) * CCH + w * 8;

  auto STAGE = [&](int kk, int bsel) {
    if constexpr (MR == 128) {
      gload16(Abase + kk * 32, (char*)(sA + bsel * ABUF) + w * 2048);
      gload16(Abase2 + kk * 32, (char*)(sA + bsel * ABUF) + w * 2048 + 1024);
    } else {
      gload16(Abase + kk * 32, (char*)(sA + bsel * ABUF) + w * 1024);
    }
    gload16(B0base + kk * 32, (char*)(sB + bsel * 4096) + w * 2048);
    gload16(B1base + kk * 32, (char*)(sB + bsel * 4096) + w * 2048 + 1024);
  };

  STAGE(0, 0);
  STAGE(1, 1);
  if constexpr (MR == 128) WAIT_BAR(4); else WAIT_BAR(3);

#pragma unroll
  for (int kk = 0; kk < 12; ++kk) {
    const int cur = kk % 3;
    const int stg = (kk + 2) % 3;
    if (kk + 2 < 12) STAGE(kk + 2, stg);
    bf16x8 af[NM], bfv[4];
#pragma unroll
    for (int m = 0; m < NM; ++m)
      af[m] = ldsb8(sA + cur * ABUF + hi * (MR * 8) + (wr * MH + m * 16 + c) * 8);
#pragma unroll
    for (int n = 0; n < 4; ++n)
      bfv[n] = ldsb8(sB + cur * 4096 + hi * 1024 + (wc * 64 + n * 16 + c) * 8);
#pragma unroll
    for (int m = 0; m < NM; ++m)
#pragma unroll
      for (int n = 0; n < 4; ++n)
        acc[m][n] = __builtin_amdgcn_mfma_f32_16x16x32_bf16(af[m], bfv[n], acc[m][n], 0, 0, 0);
    if (kk + 1 < 12) {
      if (kk + 2 < 12) {
        if constexpr (MR == 128) WAIT_BAR(4); else WAIT_BAR(3);
      } else {
        WAIT_BAR(0);
      }
    }
  }

#pragma unroll
  for (int m = 0; m < NM; ++m) {
#pragma unroll
    for (int r = 0; r < 4; ++r) {
      int row = row0 + wr * MH + m * 16 + hi * 4 + r;
#pragma unroll
      for (int n = 0; n < 4; ++n) {
        int col = col0 + wc * 64 + n * 16 + c;
        float v = (acc[m][n][r] + bias[col]) * oscale;
        if (epi == 0) {
          ((unsigned short*)out)[(size_t)row * CCH + col] =
              __builtin_bit_cast(unsigned short, (__bf16)v);
        } else if (epi == 2) {
          ((float*)out)[(size_t)row * CCH + col] = v;
        } else {
          int b_ = row / NKV, j = row - b_ * NKV;
          int h_ = col >> 5, d = col & 31;
          int loc = j & 63;
          // κ' = (n&1)*32 + hi*8 + (n>>1)*4 + r for loc = n*16 + hi*4 + r
          int kap = (j & ~63) + ((loc & 16) << 1) + ((loc & 12) << 1) +
                    ((loc & 32) >> 3) + (loc & 3);
          ((unsigned short*)out)[((size_t)((b_ * 12 + h_) * 32 + d)) * KPAD + kap] =
              __builtin_bit_cast(unsigned short, (__bf16)v);
        }
      }
    }
  }
}

// fused q/k/v projection: grid.x = 98(q,128-row) + 49(k) + 49(v), grid.y = 3
__global__ __launch_bounds__(256) void qkv_kernel(
    const unsigned short* __restrict__ xb, const unsigned short* __restrict__ xpb,
    const unsigned short* __restrict__ wq, const unsigned short* __restrict__ wk,
    const unsigned short* __restrict__ wv,
    const float* __restrict__ bq, const float* __restrict__ bk,
    const float* __restrict__ bv,
    unsigned short* __restrict__ q_b, unsigned short* __restrict__ k_b,
    unsigned short* __restrict__ vt_b) {
  __shared__ unsigned short sA[3 * 4096];
  __shared__ unsigned short sB[3 * 4096];
  int bx = blockIdx.x, cy = blockIdx.y * 128;
  if (bx < 98) {
    gemm_body<128>(xb, wq, bq, (void*)q_b, bx * 128, cy, 0, SC2, sA, sB);
  } else if (bx < 147) {
    gemm_body<64>(xpb, wk, bk, (void*)k_b, (bx - 98) * 64, cy, 0, 1.f, sA, sB);
  } else {
    gemm_body<64>(xpb, wv, bv, (void*)vt_b, (bx - 147) * 64, cy, 1, 1.f, sA, sB);
  }
}

__global__ __launch_bounds__(256) void outproj_kernel(
    const unsigned short* __restrict__ ob, const unsigned short* __restrict__ wp,
    const float* __restrict__ bp_, float* __restrict__ out) {
  __shared__ unsigned short sA[3 * 4096];
  __shared__ unsigned short sB[3 * 4096];
  gemm_body<128>(ob, wp, bp_, (void*)out, blockIdx.x * 128, blockIdx.y * 128, 2, 1.f,
                 sA, sB);
}

// ---------------- flash attention (no-max softmax, register-resident P) -----
// grid: 1200 = b*H*25, XCD-swizzled (1200 = 8 x 150: each XCD owns 6 complete
// (b,h) K/V working sets -> L2-resident re-staging). QBLK=128: 4 waves, wave
// w owns q rows {q0+g*64+16w..+16}, g=0,1. Swapped QK^T (mfma(K,Q_g)) +
// κ'-permuted V => lane-local packed P IS the PV A-fragment. KVBLK=64,
// 3-buffer depth-2 prefetch, counted vmcnt(2), fenced barriers, setprio PV.
__global__ __launch_bounds__(256) void attn_kernel(
    const unsigned short* __restrict__ qb, const unsigned short* __restrict__ kb,
    const unsigned short* __restrict__ vtb, unsigned short* __restrict__ ob) {
  __shared__ unsigned short sQ[4096];       // 2 x [4 kchunk][64 qrow] x8
  __shared__ unsigned short sK[3][2048];    // [4 kchunk][64 j] x8
  __shared__ unsigned short sV[3][2048];    // [8 κ'chunk][32 d] x8

  const int raw = blockIdx.x;               // 1200 = 8 * 150, bijective
  const int lg = (raw & 7) * 150 + (raw >> 3);
  const int qt = lg % 25;
  const int h = (lg / 25) % 12;
  const int b = lg / 300;
  const int t = threadIdx.x, w = t >> 6, l = t & 63;
  const int q0 = qt * 128;
  const int hi = l >> 4, c = l & 15;

  const unsigned short* vbase = vtb + ((size_t)((b * 12 + h) * 32 + (l & 31))) * KPAD
                                + (2 * w + (l >> 5)) * 8;

  auto stageK = [&](int ttile, int bsel) {
    int j = ttile * 64 + l; if (j > NKV - 1) j = NKV - 1;
    gload16(kb + ((size_t)(b * NKV + j)) * CCH + h * 32 + w * 8,
            (char*)sK[bsel] + w * 1024);
  };
  auto stageV = [&](int ttile, int bsel) {
    gload16(vbase + ttile * 64, (char*)sV[bsel] + w * 1024);
  };

  // prologue: Q (2 halves, rows clamped for the qt=24 tail) + tiles 0,1
  {
    int r0 = q0 + l;            if (r0 > NTOK - 1) r0 = NTOK - 1;
    int r1 = q0 + 64 + l;       if (r1 > NTOK - 1) r1 = NTOK - 1;
    gload16(qb + ((size_t)(b * NTOK + r0)) * CCH + h * 32 + w * 8,
            (char*)sQ + w * 1024);
    gload16(qb + ((size_t)(b * NTOK + r1)) * CCH + h * 32 + w * 8,
            (char*)sQ + 4096 + w * 1024);
  }
  stageK(0, 0); stageV(0, 0);
  stageK(1, 1); stageV(1, 1);
  WAIT_BAR(2);   // Q, K0, V0 landed; K1,V1 in flight

  const bf16x8 aq0 = ldsb8(&sQ[hi * 512 + (w * 16 + c) * 8]);
  const bf16x8 aq1 = ldsb8(&sQ[2048 + hi * 512 + (w * 16 + c) * 8]);
  bf16x8 ones;
#pragma unroll
  for (int i = 0; i < 8; ++i) ones[i] = (__bf16)1.0f;
  const f32x4 fz = (f32x4){0.f, 0.f, 0.f, 0.f};

  f32x4 a00 = fz, a01 = fz, al0 = fz;   // group 0: d 0-15, d 16-31, rowsum
  f32x4 a10 = fz, a11 = fz, al1 = fz;   // group 1

#pragma unroll
  for (int tt = 0; tt < 13; ++tt) {
    const int cur = tt % 3;
    const int stg = (tt + 2) % 3;
    if (tt + 2 < 13) { stageK(tt + 2, stg); stageV(tt + 2, stg); }

    // swapped QK^T, K fragment shared across both q-groups
    f32x4 s0[4], s1[4];
#pragma unroll
    for (int n = 0; n < 4; ++n) {
      bf16x8 kf = ldsb8(&sK[cur][hi * 512 + (n * 16 + c) * 8]);
      s0[n] = __builtin_amdgcn_mfma_f32_16x16x32_bf16(kf, aq0, fz, 0, 0, 0);
      s1[n] = __builtin_amdgcn_mfma_f32_16x16x32_bf16(kf, aq1, fz, 0, 0, 0);
    }

    // exp (exp2f: compiler-managed TRANS hazards) + pack per group;
    // κ' = (n&1)*32 + hi*8 + (n>>1)*4 + r
    bf16x8 pa00, pa01, pa10, pa11;   // [group][kkk]
    {
      float p[4][4];
#pragma unroll
      for (int n = 0; n < 4; ++n)
#pragma unroll
        for (int r = 0; r < 4; ++r) p[n][r] = exp2f(s0[n][r]);
      if (tt == 12)
#pragma unroll
        for (int n = 1; n < 4; ++n)
#pragma unroll
          for (int r = 0; r < 4; ++r) p[n][r] = 0.f;
#pragma unroll
      for (int rr = 0; rr < 4; ++rr) {
        pa00[rr] = (__bf16)p[0][rr]; pa00[4 + rr] = (__bf16)p[2][rr];
        pa01[rr] = (__bf16)p[1][rr]; pa01[4 + rr] = (__bf16)p[3][rr];
      }
    }
    {
      float p[4][4];
#pragma unroll
      for (int n = 0; n < 4; ++n)
#pragma unroll
        for (int r = 0; r < 4; ++r) p[n][r] = exp2f(s1[n][r]);
      if (tt == 12)
#pragma unroll
        for (int n = 1; n < 4; ++n)
#pragma unroll
          for (int r = 0; r < 4; ++r) p[n][r] = 0.f;
#pragma unroll
      for (int rr = 0; rr < 4; ++rr) {
        pa10[rr] = (__bf16)p[0][rr]; pa10[4 + rr] = (__bf16)p[2][rr];
        pa11[rr] = (__bf16)p[1][rr]; pa11[4 + rr] = (__bf16)p[3][rr];
      }
    }

    // PV + rowsum: V fragments shared across both q-groups
    __builtin_amdgcn_s_setprio(1);
#pragma unroll
    for (int kkk = 0; kkk < 2; ++kkk) {
      bf16x8 pg0 = kkk ? pa01 : pa00;
      bf16x8 pg1 = kkk ? pa11 : pa10;
      bf16x8 v0 = ldsb8(&sV[cur][(kkk * 4 + hi) * 256 + c * 8]);
      bf16x8 v1 = ldsb8(&sV[cur][(kkk * 4 + hi) * 256 + (16 + c) * 8]);
      a00 = __builtin_amdgcn_mfma_f32_16x16x32_bf16(pg0, v0, a00, 0, 0, 0);
      a10 = __builtin_amdgcn_mfma_f32_16x16x32_bf16(pg1, v0, a10, 0, 0, 0);
      a01 = __builtin_amdgcn_mfma_f32_16x16x32_bf16(pg0, v1, a01, 0, 0, 0);
      a11 = __builtin_amdgcn_mfma_f32_16x16x32_bf16(pg1, v1, a11, 0, 0, 0);
      al0 = __builtin_amdgcn_mfma_f32_16x16x32_bf16(pg0, ones, al0, 0, 0, 0);
      al1 = __builtin_amdgcn_mfma_f32_16x16x32_bf16(pg1, ones, al1, 0, 0, 0);
    }
    __builtin_amdgcn_s_setprio(0);

    if (tt + 1 < 13) {
      if (tt + 2 < 13) WAIT_BAR(2); else WAIT_BAR(0);
    }
  }

#pragma unroll
  for (int r = 0; r < 4; ++r) {
    int row = q0 + w * 16 + hi * 4 + r;           // group 0: always < NTOK
    float inv = 1.f / al0[r];
    size_t base = ((size_t)(b * NTOK + row)) * CCH + h * 32;
    ob[base + c] = __builtin_bit_cast(unsigned short, (__bf16)(a00[r] * inv));
    ob[base + 16 + c] = __builtin_bit_cast(unsigned short, (__bf16)(a01[r] * inv));
  }
#pragma unroll
  for (int r = 0; r < 4; ++r) {
    int row = q0 + 64 + w * 16 + hi * 4 + r;      // group 1: masked on tail
    if (row < NTOK) {
      float inv = 1.f / al1[r];
      size_t base = ((size_t)(b * NTOK + row)) * CCH + h * 32;
      ob[base + c] = __builtin_bit_cast(unsigned short, (__bf16)(a10[r] * inv));
      ob[base + 16 + c] = __builtin_bit_cast(unsigned short, (__bf16)(a11[r] * inv));
    }
  }
}

// ---------------- launch ----------------

extern "C" void kernel_launch(void* const* d_in, const int* in_sizes, int n_in,
                              void* d_out, int out_size, void* d_ws, size_t ws_size,
                              hipStream_t stream) {
  const float* x   = (const float*)d_in[0];
  const float* Wq  = (const float*)d_in[1];
  const float* bq  = (const float*)d_in[2];
  const float* Wk  = (const float*)d_in[3];
  const float* bk  = (const float*)d_in[4];
  const float* Wv  = (const float*)d_in[5];
  const float* bv  = (const float*)d_in[6];
  const float* Wp  = (const float*)d_in[7];
  const float* bp  = (const float*)d_in[8];
  const float* gam = (const float*)d_in[9];
  const float* bet = (const float*)d_in[10];
  const float* mea = (const float*)d_in[11];
  const float* var = (const float*)d_in[12];

  unsigned short* wq_b = (unsigned short*)d_ws;
  unsigned short* wk_b = wq_b + 147456;
  unsigned short* wv_b = wk_b + 147456;
  unsigned short* wp_b = wv_b + 147456;
  unsigned short* xb   = wp_b + 147456;          // [12544][384]
  unsigned short* x_b  = xb + 12544 * 384;       // [3136][384]
  unsigned short* q_b  = x_b + 3136 * 384;       // [12544][384] (pre-scaled)
  unsigned short* k_b  = q_b + 12544 * 384;      // [3136][384]
  unsigned short* vt_b = k_b + 3136 * 384;       // [4][12][32][832] κ'-permuted
  unsigned short* o_b  = vt_b + 1536 * KPAD;     // [12544][384]

  prep_kernel<<<1416, 256, 0, stream>>>(x, gam, bet, mea, var, Wq, Wk, Wv, Wp,
                                        xb, x_b, wq_b, wk_b, wv_b, wp_b, vt_b);
  qkv_kernel<<<dim3(196, 3), 256, 0, stream>>>(xb, x_b, wq_b, wk_b, wv_b,
                                               bq, bk, bv, q_b, k_b, vt_b);
  attn_kernel<<<1200, 256, 0, stream>>>(q_b, k_b, vt_b, o_b);
  outproj_kernel<<<dim3(98, 3), 256, 0, stream>>>(o_b, wp_b, bp, (float*)d_out);
}

// Round 15
// 78.455 us; speedup vs baseline: 1.1806x; 1.1806x over previous
//
#include <hip/hip_runtime.h>

// E-MHSA (PVT-style spatial-reduction attention), MI355X/gfx950.
// B=4, N=3136, C=384, H=12, d=32, SR=2 -> Nk=784.
// R15 = R10 + bijective XCD swizzle ONLY (FETCH 28.4->7.3MB verified in R14).
// R14's other riders reverted: exp2f (ocml fixup VALU, +~13us) -> raw
// v_exp_f32 asm (present in all passing R4-R10); setprio dropped (4-wave
// lockstep = m190-negative case). Structure: attn QBLK=128 / 4 waves /
// KVBLK=64 / 3-buffer depth-2 counted-vmcnt / register-resident P /
// κ'-permuted V; GEMMs 128x128 (q/out) + 64x128 (k/v).

typedef __bf16 bf16x8 __attribute__((ext_vector_type(8)));
typedef unsigned short u16x8 __attribute__((ext_vector_type(8)));
typedef float f32x4 __attribute__((ext_vector_type(4)));

#define NTOK 3136
#define NKV 784
#define CCH 384
#define KPAD 832                   // 13 * 64, κ'-row stride for vt
#define SC2 0.25503472078024693f   // 32^-0.5 * log2(e), folded into Q

// fence-carrying wait+barrier (N = vmcnt to leave outstanding)
#define WAIT_BAR(N) asm volatile("s_waitcnt vmcnt(" #N ")\n\ts_barrier" ::: "memory")

__device__ __forceinline__ unsigned short f2b(float f) {
  union { float f; unsigned u; } v; v.f = f;
  unsigned r = v.u + 0x7fffu + ((v.u >> 16) & 1u);   // RNE
  return (unsigned short)(r >> 16);
}

__device__ __forceinline__ bf16x8 ldsb8(const unsigned short* p) {
  u16x8 v = *(const u16x8*)p;
  return __builtin_bit_cast(bf16x8, v);
}

// async global->LDS, 16B/lane; LDS dest = wave-uniform base + lane*16
__device__ __forceinline__ void gload16(const void* g, void* lds) {
  auto* g1 = reinterpret_cast<const __attribute__((address_space(1))) unsigned int*>(
      reinterpret_cast<uintptr_t>(g));
  auto* l3 = reinterpret_cast<__attribute__((address_space(3))) unsigned int*>(
      reinterpret_cast<uintptr_t>(lds));
  __builtin_amdgcn_global_load_lds(g1, l3, 16, 0, 0);
}

// ---------------- fused prep ----------------
// [0,1176): pool+bn + cast-x ; [1176,1320): cast weights ; [1320,1416): zero vt pad
__global__ __launch_bounds__(256) void prep_kernel(
    const float* __restrict__ x, const float* __restrict__ gam,
    const float* __restrict__ bet, const float* __restrict__ mea,
    const float* __restrict__ var,
    const float* __restrict__ Wq, const float* __restrict__ Wk,
    const float* __restrict__ Wv, const float* __restrict__ Wp,
    unsigned short* __restrict__ xb, unsigned short* __restrict__ xpb,
    unsigned short* __restrict__ wq, unsigned short* __restrict__ wk,
    unsigned short* __restrict__ wv, unsigned short* __restrict__ wp,
    unsigned short* __restrict__ vt) {
  int bid = blockIdx.x;
  if (bid < 1176) {
    int i = bid * 256 + threadIdx.x;       // < 301056 = 4*784*96
    int c4 = i % 96;
    int row = i / 96;                      // b*784 + nk
    int b = row / NKV, nk = row - b * NKV;
    const float4* x4 = (const float4*)x;
    size_t base = ((size_t)(b * NTOK + nk * 4)) * 96 + c4;
    float sx = 0.f, sy = 0.f, sz = 0.f, sw = 0.f;
#pragma unroll
    for (int r = 0; r < 4; ++r) {
      float4 v = x4[base + (size_t)r * 96];
      ushort4 cv; cv.x = f2b(v.x); cv.y = f2b(v.y); cv.z = f2b(v.z); cv.w = f2b(v.w);
      ((ushort4*)xb)[base + (size_t)r * 96] = cv;
      sx += v.x; sy += v.y; sz += v.z; sw += v.w;
    }
    float4 g4 = ((const float4*)gam)[c4];
    float4 b4 = ((const float4*)bet)[c4];
    float4 m4 = ((const float4*)mea)[c4];
    float4 v4 = ((const float4*)var)[c4];
    ushort4 r4;
    r4.x = f2b((sx * 0.25f - m4.x) * rsqrtf(v4.x + 1e-5f) * g4.x + b4.x);
    r4.y = f2b((sy * 0.25f - m4.y) * rsqrtf(v4.y + 1e-5f) * g4.y + b4.y);
    r4.z = f2b((sz * 0.25f - m4.z) * rsqrtf(v4.z + 1e-5f) * g4.z + b4.z);
    r4.w = f2b((sw * 0.25f - m4.w) * rsqrtf(v4.w + 1e-5f) * g4.w + b4.w);
    ((ushort4*)xpb)[i] = r4;
  } else if (bid < 1320) {
    int i = (bid - 1176) * 256 + threadIdx.x;   // < 36864 = 147456/4
    float4 va = ((const float4*)Wq)[i];
    float4 vb = ((const float4*)Wk)[i];
    float4 vc = ((const float4*)Wv)[i];
    float4 vd = ((const float4*)Wp)[i];
    ushort4 ra; ra.x = f2b(va.x); ra.y = f2b(va.y); ra.z = f2b(va.z); ra.w = f2b(va.w);
    ushort4 rb; rb.x = f2b(vb.x); rb.y = f2b(vb.y); rb.z = f2b(vb.z); rb.w = f2b(vb.w);
    ushort4 rc; rc.x = f2b(vc.x); rc.y = f2b(vc.y); rc.z = f2b(vc.z); rc.w = f2b(vc.w);
    ushort4 rd; rd.x = f2b(vd.x); rd.y = f2b(vd.y); rd.z = f2b(vd.z); rd.w = f2b(vd.w);
    ((ushort4*)wq)[i] = ra; ((ushort4*)wk)[i] = rb;
    ((ushort4*)wv)[i] = rc; ((ushort4*)wp)[i] = rd;
  } else {
    // zero vt κ'-pad [768,832) for all 1536 (b,h,d) rows
    int i = (bid - 1320) * 256 + threadIdx.x;   // < 24576
    int row = i >> 4, quad = i & 15;
    ushort4 z; z.x = 0; z.y = 0; z.z = 0; z.w = 0;
    *(ushort4*)&vt[(size_t)row * KPAD + 768 + quad * 4] = z;
  }
}

// ---------------- GEMM body: C[MR x 128] = A[MRxK] * W[128 cols][K]^T + bias --
// MR = 64 or 128. LDS [kchunk][row] 16B units, conflict-free b128 reads.
// 3-buffer pipeline, depth-2 prefetch, counted vmcnt mid-loop, fully
// unrolled, fenced barriers.
// epi: 0 bf16 row-major (scaled by oscale), 1 bf16 κ'-scatter vt, 2 fp32.
template <int MR>
__device__ __forceinline__ void gemm_body(
    const unsigned short* __restrict__ A, const unsigned short* __restrict__ Bt,
    const float* __restrict__ bias, void* __restrict__ out,
    int row0, int col0, int epi, float oscale,
    unsigned short* sA, unsigned short* sB) {
  constexpr int ABUF = MR * 32;          // ushorts per A buffer
  constexpr int MH = MR / 2;             // rows per wave
  constexpr int NM = MR / 32;            // A fragments per wave
  const int t = threadIdx.x, w = t >> 6, l = t & 63;
  const int wr = w >> 1, wc = w & 1;
  const int hi = l >> 4, c = l & 15;

  f32x4 acc[NM][4];
#pragma unroll
  for (int m = 0; m < NM; ++m)
#pragma unroll
    for (int n = 0; n < 4; ++n) acc[m][n] = (f32x4){0.f, 0.f, 0.f, 0.f};

  const unsigned short* Abase = A + (size_t)(row0 + l) * CCH + w * 8;
  const unsigned short* Abase2 = A + (size_t)(row0 + (MR == 128 ? 64 : 0) + l) * CCH + w * 8;
  const unsigned short* B0base = Bt + (size_t)(col0 + l) * CCH + w * 8;
  const unsigned short* B1base = Bt + (size_t)(col0 + 64 + l) * CCH + w * 8;

  auto STAGE = [&](int kk, int bsel) {
    if constexpr (MR == 128) {
      gload16(Abase + kk * 32, (char*)(sA + bsel * ABUF) + w * 2048);
      gload16(Abase2 + kk * 32, (char*)(sA + bsel * ABUF) + w * 2048 + 1024);
    } else {
      gload16(Abase + kk * 32, (char*)(sA + bsel * ABUF) + w * 1024);
    }
    gload16(B0base + kk * 32, (char*)(sB + bsel * 4096) + w * 2048);
    gload16(B1base + kk * 32, (char*)(sB + bsel * 4096) + w * 2048 + 1024);
  };

  STAGE(0, 0);
  STAGE(1, 1);
  if constexpr (MR == 128) WAIT_BAR(4); else WAIT_BAR(3);

#pragma unroll
  for (int kk = 0; kk < 12; ++kk) {
    const int cur = kk % 3;
    const int stg = (kk + 2) % 3;
    if (kk + 2 < 12) STAGE(kk + 2, stg);
    bf16x8 af[NM], bfv[4];
#pragma unroll
    for (int m = 0; m < NM; ++m)
      af[m] = ldsb8(sA + cur * ABUF + hi * (MR * 8) + (wr * MH + m * 16 + c) * 8);
#pragma unroll
    for (int n = 0; n < 4; ++n)
      bfv[n] = ldsb8(sB + cur * 4096 + hi * 1024 + (wc * 64 + n * 16 + c) * 8);
#pragma unroll
    for (int m = 0; m < NM; ++m)
#pragma unroll
      for (int n = 0; n < 4; ++n)
        acc[m][n] = __builtin_amdgcn_mfma_f32_16x16x32_bf16(af[m], bfv[n], acc[m][n], 0, 0, 0);
    if (kk + 1 < 12) {
      if (kk + 2 < 12) {
        if constexpr (MR == 128) WAIT_BAR(4); else WAIT_BAR(3);
      } else {
        WAIT_BAR(0);
      }
    }
  }

#pragma unroll
  for (int m = 0; m < NM; ++m) {
#pragma unroll
    for (int r = 0; r < 4; ++r) {
      int row = row0 + wr * MH + m * 16 + hi * 4 + r;
#pragma unroll
      for (int n = 0; n < 4; ++n) {
        int col = col0 + wc * 64 + n * 16 + c;
        float v = (acc[m][n][r] + bias[col]) * oscale;
        if (epi == 0) {
          ((unsigned short*)out)[(size_t)row * CCH + col] =
              __builtin_bit_cast(unsigned short, (__bf16)v);
        } else if (epi == 2) {
          ((float*)out)[(size_t)row * CCH + col] = v;
        } else {
          int b_ = row / NKV, j = row - b_ * NKV;
          int h_ = col >> 5, d = col & 31;
          int loc = j & 63;
          // κ' = (n&1)*32 + hi*8 + (n>>1)*4 + r for loc = n*16 + hi*4 + r
          int kap = (j & ~63) + ((loc & 16) << 1) + ((loc & 12) << 1) +
                    ((loc & 32) >> 3) + (loc & 3);
          ((unsigned short*)out)[((size_t)((b_ * 12 + h_) * 32 + d)) * KPAD + kap] =
              __builtin_bit_cast(unsigned short, (__bf16)v);
        }
      }
    }
  }
}

// fused q/k/v projection: grid.x = 98(q,128-row) + 49(k) + 49(v), grid.y = 3
__global__ __launch_bounds__(256) void qkv_kernel(
    const unsigned short* __restrict__ xb, const unsigned short* __restrict__ xpb,
    const unsigned short* __restrict__ wq, const unsigned short* __restrict__ wk,
    const unsigned short* __restrict__ wv,
    const float* __restrict__ bq, const float* __restrict__ bk,
    const float* __restrict__ bv,
    unsigned short* __restrict__ q_b, unsigned short* __restrict__ k_b,
    unsigned short* __restrict__ vt_b) {
  __shared__ unsigned short sA[3 * 4096];
  __shared__ unsigned short sB[3 * 4096];
  int bx = blockIdx.x, cy = blockIdx.y * 128;
  if (bx < 98) {
    gemm_body<128>(xb, wq, bq, (void*)q_b, bx * 128, cy, 0, SC2, sA, sB);
  } else if (bx < 147) {
    gemm_body<64>(xpb, wk, bk, (void*)k_b, (bx - 98) * 64, cy, 0, 1.f, sA, sB);
  } else {
    gemm_body<64>(xpb, wv, bv, (void*)vt_b, (bx - 147) * 64, cy, 1, 1.f, sA, sB);
  }
}

__global__ __launch_bounds__(256) void outproj_kernel(
    const unsigned short* __restrict__ ob, const unsigned short* __restrict__ wp,
    const float* __restrict__ bp_, float* __restrict__ out) {
  __shared__ unsigned short sA[3 * 4096];
  __shared__ unsigned short sB[3 * 4096];
  gemm_body<128>(ob, wp, bp_, (void*)out, blockIdx.x * 128, blockIdx.y * 128, 2, 1.f,
                 sA, sB);
}

// ---------------- flash attention (no-max softmax, register-resident P) -----
// grid: 1200 = b*H*25, XCD-swizzled (1200 = 8 x 150: each XCD owns 6 complete
// (b,h) K/V working sets -> L2-resident re-staging; FETCH 28.4->7.3MB, R14).
// QBLK=128: 4 waves, wave w owns q rows {q0+g*64+16w..+16}, g=0,1.
// Swapped QK^T (mfma(K,Q_g)) + κ'-permuted V => lane-local packed P IS the
// PV A-fragment. KVBLK=64, 3-buffer depth-2, counted vmcnt(2), fenced bars.
__global__ __launch_bounds__(256) void attn_kernel(
    const unsigned short* __restrict__ qb, const unsigned short* __restrict__ kb,
    const unsigned short* __restrict__ vtb, unsigned short* __restrict__ ob) {
  __shared__ unsigned short sQ[4096];       // 2 x [4 kchunk][64 qrow] x8
  __shared__ unsigned short sK[3][2048];    // [4 kchunk][64 j] x8
  __shared__ unsigned short sV[3][2048];    // [8 κ'chunk][32 d] x8

  const int raw = blockIdx.x;               // 1200 = 8 * 150, bijective
  const int lg = (raw & 7) * 150 + (raw >> 3);
  const int qt = lg % 25;
  const int h = (lg / 25) % 12;
  const int b = lg / 300;
  const int t = threadIdx.x, w = t >> 6, l = t & 63;
  const int q0 = qt * 128;
  const int hi = l >> 4, c = l & 15;

  const unsigned short* vbase = vtb + ((size_t)((b * 12 + h) * 32 + (l & 31))) * KPAD
                                + (2 * w + (l >> 5)) * 8;

  auto stageK = [&](int ttile, int bsel) {
    int j = ttile * 64 + l; if (j > NKV - 1) j = NKV - 1;
    gload16(kb + ((size_t)(b * NKV + j)) * CCH + h * 32 + w * 8,
            (char*)sK[bsel] + w * 1024);
  };
  auto stageV = [&](int ttile, int bsel) {
    gload16(vbase + ttile * 64, (char*)sV[bsel] + w * 1024);
  };

  // prologue: Q (2 halves, rows clamped for the qt=24 tail) + tiles 0,1
  {
    int r0 = q0 + l;            if (r0 > NTOK - 1) r0 = NTOK - 1;
    int r1 = q0 + 64 + l;       if (r1 > NTOK - 1) r1 = NTOK - 1;
    gload16(qb + ((size_t)(b * NTOK + r0)) * CCH + h * 32 + w * 8,
            (char*)sQ + w * 1024);
    gload16(qb + ((size_t)(b * NTOK + r1)) * CCH + h * 32 + w * 8,
            (char*)sQ + 4096 + w * 1024);
  }
  stageK(0, 0); stageV(0, 0);
  stageK(1, 1); stageV(1, 1);
  WAIT_BAR(2);   // Q, K0, V0 landed; K1,V1 in flight

  const bf16x8 aq0 = ldsb8(&sQ[hi * 512 + (w * 16 + c) * 8]);
  const bf16x8 aq1 = ldsb8(&sQ[2048 + hi * 512 + (w * 16 + c) * 8]);
  bf16x8 ones;
#pragma unroll
  for (int i = 0; i < 8; ++i) ones[i] = (__bf16)1.0f;
  const f32x4 fz = (f32x4){0.f, 0.f, 0.f, 0.f};

  f32x4 a00 = fz, a01 = fz, al0 = fz;   // group 0: d 0-15, d 16-31, rowsum
  f32x4 a10 = fz, a11 = fz, al1 = fz;   // group 1

#pragma unroll
  for (int tt = 0; tt < 13; ++tt) {
    const int cur = tt % 3;
    const int stg = (tt + 2) % 3;
    if (tt + 2 < 13) { stageK(tt + 2, stg); stageV(tt + 2, stg); }

    // swapped QK^T, K fragment shared across both q-groups
    f32x4 s0[4], s1[4];
#pragma unroll
    for (int n = 0; n < 4; ++n) {
      bf16x8 kf = ldsb8(&sK[cur][hi * 512 + (n * 16 + c) * 8]);
      s0[n] = __builtin_amdgcn_mfma_f32_16x16x32_bf16(kf, aq0, fz, 0, 0, 0);
      s1[n] = __builtin_amdgcn_mfma_f32_16x16x32_bf16(kf, aq1, fz, 0, 0, 0);
    }

    // exp + pack per group; κ' = (n&1)*32 + hi*8 + (n>>1)*4 + r
    bf16x8 pa00, pa01, pa10, pa11;   // [group][kkk]
    {
      float p[4][4];
#pragma unroll
      for (int n = 0; n < 4; ++n)
#pragma unroll
        for (int r = 0; r < 4; ++r) {
          float e;
          asm("v_exp_f32 %0, %1" : "=v"(e) : "v"(s0[n][r]));
          p[n][r] = e;
        }
      if (tt == 12)
#pragma unroll
        for (int n = 1; n < 4; ++n)
#pragma unroll
          for (int r = 0; r < 4; ++r) p[n][r] = 0.f;
#pragma unroll
      for (int rr = 0; rr < 4; ++rr) {
        pa00[rr] = (__bf16)p[0][rr]; pa00[4 + rr] = (__bf16)p[2][rr];
        pa01[rr] = (__bf16)p[1][rr]; pa01[4 + rr] = (__bf16)p[3][rr];
      }
    }
    {
      float p[4][4];
#pragma unroll
      for (int n = 0; n < 4; ++n)
#pragma unroll
        for (int r = 0; r < 4; ++r) {
          float e;
          asm("v_exp_f32 %0, %1" : "=v"(e) : "v"(s1[n][r]));
          p[n][r] = e;
        }
      if (tt == 12)
#pragma unroll
        for (int n = 1; n < 4; ++n)
#pragma unroll
          for (int r = 0; r < 4; ++r) p[n][r] = 0.f;
#pragma unroll
      for (int rr = 0; rr < 4; ++rr) {
        pa10[rr] = (__bf16)p[0][rr]; pa10[4 + rr] = (__bf16)p[2][rr];
        pa11[rr] = (__bf16)p[1][rr]; pa11[4 + rr] = (__bf16)p[3][rr];
      }
    }

    // PV + rowsum: V fragments shared across both q-groups
#pragma unroll
    for (int kkk = 0; kkk < 2; ++kkk) {
      bf16x8 pg0 = kkk ? pa01 : pa00;
      bf16x8 pg1 = kkk ? pa11 : pa10;
      bf16x8 v0 = ldsb8(&sV[cur][(kkk * 4 + hi) * 256 + c * 8]);
      bf16x8 v1 = ldsb8(&sV[cur][(kkk * 4 + hi) * 256 + (16 + c) * 8]);
      a00 = __builtin_amdgcn_mfma_f32_16x16x32_bf16(pg0, v0, a00, 0, 0, 0);
      a10 = __builtin_amdgcn_mfma_f32_16x16x32_bf16(pg1, v0, a10, 0, 0, 0);
      a01 = __builtin_amdgcn_mfma_f32_16x16x32_bf16(pg0, v1, a01, 0, 0, 0);
      a11 = __builtin_amdgcn_mfma_f32_16x16x32_bf16(pg1, v1, a11, 0, 0, 0);
      al0 = __builtin_amdgcn_mfma_f32_16x16x32_bf16(pg0, ones, al0, 0, 0, 0);
      al1 = __builtin_amdgcn_mfma_f32_16x16x32_bf16(pg1, ones, al1, 0, 0, 0);
    }

    if (tt + 1 < 13) {
      if (tt + 2 < 13) WAIT_BAR(2); else WAIT_BAR(0);
    }
  }

#pragma unroll
  for (int r = 0; r < 4; ++r) {
    int row = q0 + w * 16 + hi * 4 + r;           // group 0: always < NTOK
    float inv = 1.f / al0[r];
    size_t base = ((size_t)(b * NTOK + row)) * CCH + h * 32;
    ob[base + c] = __builtin_bit_cast(unsigned short, (__bf16)(a00[r] * inv));
    ob[base + 16 + c] = __builtin_bit_cast(unsigned short, (__bf16)(a01[r] * inv));
  }
#pragma unroll
  for (int r = 0; r < 4; ++r) {
    int row = q0 + 64 + w * 16 + hi * 4 + r;      // group 1: masked on tail
    if (row < NTOK) {
      float inv = 1.f / al1[r];
      size_t base = ((size_t)(b * NTOK + row)) * CCH + h * 32;
      ob[base + c] = __builtin_bit_cast(unsigned short, (__bf16)(a10[r] * inv));
      ob[base + 16 + c] = __builtin_bit_cast(unsigned short, (__bf16)(a11[r] * inv));
    }
  }
}

// ---------------- launch ----------------

extern "C" void kernel_launch(void* const* d_in, const int* in_sizes, int n_in,
                              void* d_out, int out_size, void* d_ws, size_t ws_size,
                              hipStream_t stream) {
  const float* x   = (const float*)d_in[0];
  const float* Wq  = (const float*)d_in[1];
  const float* bq  = (const float*)d_in[2];
  const float* Wk  = (const float*)d_in[3];
  const float* bk  = (const float*)d_in[4];
  const float* Wv  = (const float*)d_in[5];
  const float* bv  = (const float*)d_in[6];
  const float* Wp  = (const float*)d_in[7];
  const float* bp  = (const float*)d_in[8];
  const float* gam = (const float*)d_in[9];
  const float* bet = (const float*)d_in[10];
  const float* mea = (const float*)d_in[11];
  const float* var = (const float*)d_in[12];

  unsigned short* wq_b = (unsigned short*)d_ws;
  unsigned short* wk_b = wq_b + 147456;
  unsigned short* wv_b = wk_b + 147456;
  unsigned short* wp_b = wv_b + 147456;
  unsigned short* xb   = wp_b + 147456;          // [12544][384]
  unsigned short* x_b  = xb + 12544 * 384;       // [3136][384]
  unsigned short* q_b  = x_b + 3136 * 384;       // [12544][384] (pre-scaled)
  unsigned short* k_b  = q_b + 12544 * 384;      // [3136][384]
  unsigned short* vt_b = k_b + 3136 * 384;       // [4][12][32][832] κ'-permuted
  unsigned short* o_b  = vt_b + 1536 * KPAD;     // [12544][384]

  prep_kernel<<<1416, 256, 0, stream>>>(x, gam, bet, mea, var, Wq, Wk, Wv, Wp,
                                        xb, x_b, wq_b, wk_b, wv_b, wp_b, vt_b);
  qkv_kernel<<<dim3(196, 3), 256, 0, stream>>>(xb, x_b, wq_b, wk_b, wv_b,
                                               bq, bk, bv, q_b, k_b, vt_b);
  attn_kernel<<<1200, 256, 0, stream>>>(q_b, k_b, vt_b, o_b);
  outproj_kernel<<<dim3(98, 3), 256, 0, stream>>>(o_b, wp_b, bp, (float*)d_out);
}